// Round 3
// baseline (222.432 us; speedup 1.0000x reference)
//
#include <hip/hip_runtime.h>
#include <math.h>

#define ALPHA 32.0f
#define MRG 0.1f
#define STAT_WEIGHT 0.01f
#define STAT_ADJ_W 0.15f
#define COS_EPS 1e-8f

typedef __attribute__((ext_vector_type(8))) short bf16x8;
typedef __attribute__((ext_vector_type(4))) float f32x4;

__device__ __forceinline__ ushort f2bf(float f) {
    unsigned u = __float_as_uint(f);
    unsigned r = (u + 0x7FFFu + ((u >> 16) & 1u)) >> 16;   // RNE
    return (ushort)r;
}

// ---------------- K1: Xn = l2_norm(X) -> fp32 + bf16; zero scal ----------------
__global__ void k_norm_x(const float* __restrict__ X, float* __restrict__ Xn,
                         ushort* __restrict__ Xn16, float* __restrict__ scal) {
    int b = blockIdx.x, d = threadIdx.x;
    if (b == 0 && d < 8) scal[d] = 0.f;
    __shared__ float red[128];
    float v = X[b * 128 + d];
    red[d] = v * v;
    __syncthreads();
    #pragma unroll
    for (int s = 64; s > 0; s >>= 1) {
        if (d < s) red[d] += red[d + s];
        __syncthreads();
    }
    float xn = v / sqrtf(red[0] + 1e-12f);
    Xn[b * 128 + d] = xn;
    Xn16[b * 128 + d] = f2bf(xn);
}

// ---------------- K2: proxy row norms + censim + adj=0 + |cc| sum --------------
// 16 rows per block, 16 threads per row (8 floats each).
__global__ void k_pnorm(const float* __restrict__ proxies, const float* __restrict__ cc,
                        float* __restrict__ pinv, float* __restrict__ censim,
                        float* __restrict__ adj, float* __restrict__ scal, int C) {
    const int tid = threadIdx.x;
    const int r = tid >> 4, s = tid & 15;
    const int c = blockIdx.x * 16 + r;
    const bool valid = (c < C);
    const int cl = valid ? c : C - 1;
    const float4* pp = (const float4*)(proxies + (size_t)cl * 128 + s * 8);
    const float4* cp = (const float4*)(cc      + (size_t)cl * 128 + s * 8);
    float4 p0 = pp[0], p1 = pp[1];
    float4 q0 = cp[0], q1 = cp[1];
    float s2 = p0.x*p0.x + p0.y*p0.y + p0.z*p0.z + p0.w*p0.w
             + p1.x*p1.x + p1.y*p1.y + p1.z*p1.z + p1.w*p1.w;
    float c2 = q0.x*q0.x + q0.y*q0.y + q0.z*q0.z + q0.w*q0.w
             + q1.x*q1.x + q1.y*q1.y + q1.z*q1.z + q1.w*q1.w;
    float pc = p0.x*q0.x + p0.y*q0.y + p0.z*q0.z + p0.w*q0.w
             + p1.x*q1.x + p1.y*q1.y + p1.z*q1.z + p1.w*q1.w;
    float ab = fabsf(q0.x)+fabsf(q0.y)+fabsf(q0.z)+fabsf(q0.w)
             + fabsf(q1.x)+fabsf(q1.y)+fabsf(q1.z)+fabsf(q1.w);
    if (!valid) ab = 0.f;
    #pragma unroll
    for (int off = 1; off < 16; off <<= 1) {
        s2 += __shfl_xor(s2, off);
        c2 += __shfl_xor(c2, off);
        pc += __shfl_xor(pc, off);
    }
    if (valid && s == 0) {
        float inv = 1.0f / sqrtf(s2 + 1e-12f);
        pinv[c] = inv;
        float pn = fmaxf(sqrtf(s2) * inv, COS_EPS);
        float cn = fmaxf(sqrtf(c2), COS_EPS);
        censim[c] = (pc * inv) / (pn * cn);
        adj[c] = 0.f;
    }
    #pragma unroll
    for (int off = 16; off < 64; off <<= 1) ab += __shfl_xor(ab, off);
    __shared__ float wsum[4];
    if ((tid & 63) == 0) wsum[tid >> 6] = ab;
    __syncthreads();
    if (tid == 0) atomicAdd(&scal[2], wsum[0] + wsum[1] + wsum[2] + wsum[3]);
}

// ---------------- K3: per-present-class stats -> adj[c], num_valid -------------
__global__ void k_stats(const float* __restrict__ Xn, const int* __restrict__ T,
                        const float* __restrict__ censim,
                        float* __restrict__ adj, float* __restrict__ scal,
                        int B, int D) {
    int b = blockIdx.x, d = threadIdx.x;   // 128 threads
    __shared__ int Tl[512];
    __shared__ float r1[128];
    for (int i = d; i < B; i += 128) Tl[i] = T[i];
    __syncthreads();
    int c = Tl[b];

    float sd = 0.f, qd = 0.f;
    int cnt = 0, minj = -1;
    for (int j = 0; j < B; ++j) {
        if (Tl[j] == c) {
            float x = Xn[(size_t)j * D + d];
            sd += x; qd += x * x;
            if (minj < 0) minj = j;
            cnt++;
        }
    }
    float fc = (float)cnt;
    float m = sd / fc;
    float var = qd / fc - m * m;
    var = fminf(fmaxf(var, 1e-6f), 10.0f);
    r1[d] = var;
    __syncthreads();
    #pragma unroll
    for (int s = 64; s > 0; s >>= 1) {
        if (d < s) r1[d] += r1[d + s];
        __syncthreads();
    }
    if (d == 0) {
        float mvar = r1[0] / (float)D;
        float vw = 1.0f / (1.0f + mvar);
        adj[c] = censim[c] * vw * STAT_ADJ_W;
        if (minj == b) atomicAdd(&scal[3], 1.0f);
    }
}

// ---------------- K4: barrier-free bf16 MFMA GEMM + fused epilogue -------------
// Block: 64 classes x 512 rows. Wave wv owns rows [chunk*64+wv*16, +16).
// B-fragments built from raw fp32 proxies * pinv (bf16 in-register), hoisted.
// A-fragments read straight from L2-resident Xn16. No __syncthreads in K-loop.
__launch_bounds__(256, 3)
__global__ void k_main(const float* __restrict__ proxies, const float* __restrict__ pinv,
                       const ushort* __restrict__ Xn16, const int* __restrict__ T,
                       const float* __restrict__ adj, float* __restrict__ scal,
                       int B, int C) {
    __shared__ float Pred[4][64], Nred[4][64];
    const int tid  = threadIdx.x;
    const int lane = tid & 63;
    const int wv   = tid >> 6;
    const int nlo  = lane & 15;
    const int quad = lane >> 4;
    const int c0   = blockIdx.x * 64;

    bf16x8 bfr[4][4];
    float adjv[4];
    #pragma unroll
    for (int t = 0; t < 4; ++t) {
        int cg = c0 + t * 16 + nlo;
        int cl = (cg < C) ? cg : C - 1;
        float pin = pinv[cl];
        adjv[t] = (cg < C) ? adj[cg] : 0.f;
        #pragma unroll
        for (int ks = 0; ks < 4; ++ks) {
            const float4* src = (const float4*)(proxies + (size_t)cl * 128 + ks * 32 + quad * 8);
            float4 a = src[0], b = src[1];
            bf16x8 f;
            f[0] = (short)f2bf(a.x * pin); f[1] = (short)f2bf(a.y * pin);
            f[2] = (short)f2bf(a.z * pin); f[3] = (short)f2bf(a.w * pin);
            f[4] = (short)f2bf(b.x * pin); f[5] = (short)f2bf(b.y * pin);
            f[6] = (short)f2bf(b.z * pin); f[7] = (short)f2bf(b.w * pin);
            bfr[t][ks] = f;
        }
    }

    float pp[4] = {0, 0, 0, 0}, np[4] = {0, 0, 0, 0};
    const ushort* xbase = Xn16 + (size_t)(wv * 16 + nlo) * 128 + quad * 8;

    #pragma unroll 2
    for (int chunk = 0; chunk < 8; ++chunk) {
        const ushort* xrow = xbase + (size_t)chunk * 64 * 128;
        f32x4 acc[4] = {{0,0,0,0},{0,0,0,0},{0,0,0,0},{0,0,0,0}};
        #pragma unroll
        for (int ks = 0; ks < 4; ++ks) {
            bf16x8 af = *(const bf16x8*)(xrow + ks * 32);
            #pragma unroll
            for (int t = 0; t < 4; ++t)
                acc[t] = __builtin_amdgcn_mfma_f32_16x16x32_bf16(af, bfr[t][ks], acc[t], 0, 0, 0);
        }
        int4 tv4 = *(const int4*)(T + chunk * 64 + wv * 16 + quad * 4);
        int tvs[4] = {tv4.x, tv4.y, tv4.z, tv4.w};
        #pragma unroll
        for (int t = 0; t < 4; ++t) {
            int cls = c0 + t * 16 + nlo;
            if (cls < C) {
                #pragma unroll
                for (int r = 0; r < 4; ++r) {
                    float comb = acc[t][r] + adjv[t];
                    if (tvs[r] == cls) pp[t] += __expf(-ALPHA * (comb - MRG));
                    else               np[t] += __expf( ALPHA * (comb + MRG));
                }
            }
        }
    }

    #pragma unroll
    for (int t = 0; t < 4; ++t) {
        #pragma unroll
        for (int off = 16; off < 64; off <<= 1) {
            pp[t] += __shfl_xor(pp[t], off);
            np[t] += __shfl_xor(np[t], off);
        }
    }
    if (lane < 16) {
        #pragma unroll
        for (int t = 0; t < 4; ++t) {
            Pred[wv][t * 16 + lane] = pp[t];
            Nred[wv][t * 16 + lane] = np[t];
        }
    }
    __syncthreads();
    if (tid < 64) {
        float lp = 0.f, ln = 0.f;
        int cls = c0 + tid;
        if (cls < C) {
            float ps = Pred[0][tid] + Pred[1][tid] + Pred[2][tid] + Pred[3][tid];
            float ns = Nred[0][tid] + Nred[1][tid] + Nred[2][tid] + Nred[3][tid];
            lp = log1pf(ps);
            ln = log1pf(ns);
        }
        #pragma unroll
        for (int off = 32; off > 0; off >>= 1) {
            lp += __shfl_down(lp, off);
            ln += __shfl_down(ln, off);
        }
        if (tid == 0) {
            atomicAdd(&scal[0], lp);
            atomicAdd(&scal[1], ln);
        }
    }
}

// ---------------- K5: finalize --------------------------------------------------
__global__ void k_final(const float* __restrict__ scal, float* __restrict__ out,
                        int C, int D) {
    float num_valid = scal[3];
    float center_reg = scal[2] / ((float)C * (float)D);
    out[0] = scal[0] / num_valid + scal[1] / (float)C + STAT_WEIGHT * center_reg;
}

extern "C" void kernel_launch(void* const* d_in, const int* in_sizes, int n_in,
                              void* d_out, int out_size, void* d_ws, size_t ws_size,
                              hipStream_t stream) {
    const float* X       = (const float*)d_in[0];
    const int*   T       = (const int*)d_in[1];
    const float* proxies = (const float*)d_in[2];
    const float* cc      = (const float*)d_in[3];
    float* out = (float*)d_out;

    const int B = in_sizes[1];            // 512
    const int D = in_sizes[0] / B;        // 128
    const int C = in_sizes[2] / D;        // 50000

    float*  Xn     = (float*)d_ws;                    // B*D fp32
    float*  pinv   = Xn + (size_t)B * D;              // C fp32
    float*  censim = pinv + C;                        // C fp32
    float*  adj    = censim + C;                      // C fp32
    float*  scal   = adj + C;                         // 8 fp32
    ushort* Xn16   = (ushort*)(scal + 8);             // B*D bf16

    k_norm_x<<<B, D, 0, stream>>>(X, Xn, Xn16, scal);
    k_pnorm<<<(C + 15) / 16, 256, 0, stream>>>(proxies, cc, pinv, censim, adj, scal, C);
    k_stats<<<B, D, 0, stream>>>(Xn, T, censim, adj, scal, B, D);
    k_main<<<(C + 63) / 64, 256, 0, stream>>>(proxies, pinv, Xn16, T, adj, scal, B, C);
    k_final<<<1, 1, 0, stream>>>(scal, out, C, D);
}